// Round 1
// baseline (187.603 us; speedup 1.0000x reference)
//
#include <hip/hip_runtime.h>

// Problem: B=4, DIN=DM=256, N=256, L=64, H=4, LH=16.
// Fully fused per (b,n): grid = B*N = 1024 blocks, 512 threads (8 waves).
// Pipeline per block:
//   stage X (fp32 global -> bf16 LDS, two-hop transpose to c-contiguous blocked)
//   q^T = X^T W^T + b ; k^T likewise ; v = W X + b   (32x32x16 bf16 MFMA)
//   per head h: S^T = mfma(Kfrag, Qfrag) (K=16), lane-local softmax over e,
//               O^T = mfma(Vfrag, Pfrag) (P^T frags built via pack+shfl_xor(32))
//   out = Wo att + bo -> global fp32
// Weights pre-converted fp32->bf16 into d_ws (512 KB) by cvt_weights.

typedef unsigned int u32;
typedef unsigned short u16;
typedef __attribute__((ext_vector_type(8))) short s8v;    // 8 x bf16 (4 VGPR)
typedef __attribute__((ext_vector_type(16))) float f16v;  // 16 x f32 acc

#define XB 0        // blocked X^T / att buffer: [cblk 0..31][l 0..63][j 0..7]
#define QB 16384    // q blocked: [lblk 0..7][d 0..255][j 0..7]
#define KB 32768
#define VB 49152    // v blocked: [eblk 0..31][l 0..63][j 0..7]

__device__ __forceinline__ u16 f2bf(float x) {
  union { float f; u32 u; } c; c.f = x;
  return (u16)((c.u + 0x7FFFu + ((c.u >> 16) & 1u)) >> 16);  // RNE
}
__device__ __forceinline__ u32 pk2(float a, float b) {
  return (u32)f2bf(a) | ((u32)f2bf(b) << 16);
}

__global__ void cvt_weights(const float* __restrict__ wq, const float* __restrict__ wk,
                            const float* __restrict__ wv, const float* __restrict__ wo,
                            u16* __restrict__ out) {
  int i = blockIdx.x * 256 + threadIdx.x;  // 0..65535
  out[i]          = f2bf(wq[i]);
  out[i + 65536]  = f2bf(wk[i]);
  out[i + 131072] = f2bf(wv[i]);
  out[i + 196608] = f2bf(wo[i]);
}

// ---- staging: global fp32 X[c][l] (l contig) -> linear bf16 lds[c*64+l] ----
__device__ __forceinline__ void stage_lin(const float* __restrict__ src, u16* lds,
                                          int dst, int tid) {
#pragma unroll
  for (int p = 0; p < 8; ++p) {
    int f4 = p * 512 + tid;            // 0..4095 float4s
    int c = f4 >> 4;
    int l4 = (f4 & 15) << 2;
    const float4 v = *reinterpret_cast<const float4*>(src + c * 16384 + l4);
    uint2 w; w.x = pk2(v.x, v.y); w.y = pk2(v.z, v.w);
    *reinterpret_cast<uint2*>(&lds[dst + c * 64 + l4]) = w;
  }
}

// ---- linear lds[c][l] -> blocked XB[cblk][l][j] (c-contiguous 16B groups) ----
__device__ __forceinline__ void lin_to_xb(u16* lds, int srcoff, int tid) {
  int l = tid & 63, cg = tid >> 6;
#pragma unroll
  for (int it = 0; it < 4; ++it) {
    int cb = (it << 3) + cg;                 // 0..31
    int sb = srcoff + cb * 512 + l;          // (cb*8+j)*64 + l
    u32 u0 = (u32)lds[sb]       | ((u32)lds[sb + 64]  << 16);
    u32 u1 = (u32)lds[sb + 128] | ((u32)lds[sb + 192] << 16);
    u32 u2 = (u32)lds[sb + 256] | ((u32)lds[sb + 320] << 16);
    u32 u3 = (u32)lds[sb + 384] | ((u32)lds[sb + 448] << 16);
    union { u32 u[4]; s8v v; } pw;
    pw.u[0] = u0; pw.u[1] = u1; pw.u[2] = u2; pw.u[3] = u3;
    *reinterpret_cast<s8v*>(&lds[XB + cb * 512 + l * 8]) = pw.v;
  }
}

// ---- q^T / k^T projection: D[l][o] = sum_c X^T[l][c] W[o][c] + b[o] ----
__device__ __forceinline__ void proj_T(u16* lds, const u16* __restrict__ w,
                                       const float* __restrict__ bias, int dstoff,
                                       int wid, int lo, int hi) {
  const int o = wid * 32 + lo;
  f16v a0, a1;
#pragma unroll
  for (int i = 0; i < 16; ++i) { a0[i] = 0.f; a1[i] = 0.f; }
#pragma unroll
  for (int s = 0; s < 16; ++s) {
    const s8v bw = *reinterpret_cast<const s8v*>(w + o * 256 + s * 16 + hi * 8);
    const s8v x0 = *reinterpret_cast<const s8v*>(&lds[XB + (2 * s + hi) * 512 + lo * 8]);
    const s8v x1 = *reinterpret_cast<const s8v*>(&lds[XB + (2 * s + hi) * 512 + (32 + lo) * 8]);
    a0 = __builtin_amdgcn_mfma_f32_32x32x16_bf16(x0, bw, a0, 0, 0, 0);
    a1 = __builtin_amdgcn_mfma_f32_32x32x16_bf16(x1, bw, a1, 0, 0, 0);
  }
  const float bb = bias[o];
#pragma unroll
  for (int mt = 0; mt < 2; ++mt) {
    const f16v& ac = mt ? a1 : a0;
#pragma unroll
    for (int g = 0; g < 4; ++g) {
      uint2 wv2;
      wv2.x = pk2(ac[4 * g + 0] + bb, ac[4 * g + 1] + bb);
      wv2.y = pk2(ac[4 * g + 2] + bb, ac[4 * g + 3] + bb);
      // l = 32*mt + 8*g + 4*hi + i  -> lblk = 4*mt+g, j = 4*hi+i
      *reinterpret_cast<uint2*>(&lds[dstoff + (4 * mt + g) * 2048 + o * 8 + hi * 4]) = wv2;
    }
  }
}

// ---- v projection (normal orientation): D[e][l] = sum_c Wv[e][c] X[c][l] + bv[e] ----
__device__ __forceinline__ void proj_V(u16* lds, const u16* __restrict__ w,
                                       const float* __restrict__ bias,
                                       int wid, int lo, int hi) {
  const int e0 = wid * 32;
  const int e = e0 + lo;
  f16v a0, a1;
#pragma unroll
  for (int i = 0; i < 16; ++i) { a0[i] = 0.f; a1[i] = 0.f; }
#pragma unroll
  for (int s = 0; s < 16; ++s) {
    const s8v aw = *reinterpret_cast<const s8v*>(w + e * 256 + s * 16 + hi * 8);
    const s8v x0 = *reinterpret_cast<const s8v*>(&lds[XB + (2 * s + hi) * 512 + lo * 8]);
    const s8v x1 = *reinterpret_cast<const s8v*>(&lds[XB + (2 * s + hi) * 512 + (32 + lo) * 8]);
    a0 = __builtin_amdgcn_mfma_f32_32x32x16_bf16(aw, x0, a0, 0, 0, 0);
    a1 = __builtin_amdgcn_mfma_f32_32x32x16_bf16(aw, x1, a1, 0, 0, 0);
  }
#pragma unroll
  for (int nt = 0; nt < 2; ++nt) {
    const f16v& ac = nt ? a1 : a0;
    const int l = nt * 32 + lo;
#pragma unroll
    for (int g = 0; g < 4; ++g) {
      const int eb = e0 + 8 * g + 4 * hi;  // e row of reg 4g+i is eb+i
      uint2 wv2;
      wv2.x = pk2(ac[4 * g + 0] + bias[eb + 0], ac[4 * g + 1] + bias[eb + 1]);
      wv2.y = pk2(ac[4 * g + 2] + bias[eb + 2], ac[4 * g + 3] + bias[eb + 3]);
      *reinterpret_cast<uint2*>(&lds[VB + (4 * wid + g) * 512 + l * 8 + hi * 4]) = wv2;
    }
  }
}

// ---- output projection: out[o][l] = sum_d Wo[o][d] att[d][l] + bo[o] ----
__device__ __forceinline__ void proj_O(u16* lds, const u16* __restrict__ w,
                                       const float* __restrict__ bias,
                                       float* __restrict__ out, int obase,
                                       int wid, int lo, int hi) {
  const int o0 = wid * 32;
  const int o = o0 + lo;
  f16v a0, a1;
#pragma unroll
  for (int i = 0; i < 16; ++i) { a0[i] = 0.f; a1[i] = 0.f; }
#pragma unroll
  for (int s = 0; s < 16; ++s) {
    const s8v aw = *reinterpret_cast<const s8v*>(w + o * 256 + s * 16 + hi * 8);
    const s8v b0 = *reinterpret_cast<const s8v*>(&lds[XB + (2 * s + hi) * 512 + lo * 8]);
    const s8v b1 = *reinterpret_cast<const s8v*>(&lds[XB + (2 * s + hi) * 512 + (32 + lo) * 8]);
    a0 = __builtin_amdgcn_mfma_f32_32x32x16_bf16(aw, b0, a0, 0, 0, 0);
    a1 = __builtin_amdgcn_mfma_f32_32x32x16_bf16(aw, b1, a1, 0, 0, 0);
  }
#pragma unroll
  for (int nt = 0; nt < 2; ++nt) {
    const f16v& ac = nt ? a1 : a0;
    const int l = nt * 32 + lo;
#pragma unroll
    for (int r = 0; r < 16; ++r) {
      const int orow = o0 + (r & 3) + 8 * (r >> 2) + 4 * hi;
      out[obase + orow * 16384 + l] = ac[r] + bias[orow];
    }
  }
}

__global__ __launch_bounds__(512)
void mha_kernel(const float* __restrict__ xq, const float* __restrict__ xk,
                const float* __restrict__ xv, const u16* __restrict__ wb,
                const float* __restrict__ bq, const float* __restrict__ bk,
                const float* __restrict__ bv, const float* __restrict__ bo,
                float* __restrict__ out) {
  __shared__ __align__(16) u16 lds[65536];  // 128 KB
  const int tid = threadIdx.x;
  const int lane = tid & 63;
  const int wid = tid >> 6;
  const int lo = lane & 31;
  const int hi = lane >> 5;
  const int b = blockIdx.x >> 8, n = blockIdx.x & 255;
  const int base = b * 4194304 + n * 64;

  // ---- projections (staging for next input overlapped with current GEMM) ----
  stage_lin(xq + base, lds, QB, tid);
  __syncthreads();
  lin_to_xb(lds, QB, tid);
  __syncthreads();
  stage_lin(xk + base, lds, KB, tid);          // prefetch K while computing q
  proj_T(lds, wb + 0, bq, QB, wid, lo, hi);
  __syncthreads();
  lin_to_xb(lds, KB, tid);
  __syncthreads();
  stage_lin(xv + base, lds, VB, tid);          // prefetch V while computing k
  proj_T(lds, wb + 65536, bk, KB, wid, lo, hi);
  __syncthreads();
  lin_to_xb(lds, VB, tid);
  __syncthreads();
  proj_V(lds, wb + 131072, bv, wid, lo, hi);
  __syncthreads();

  // ---- attention: wave owns d-band [32*wid, 32*wid+32) ----
  f16v z16;
#pragma unroll
  for (int i = 0; i < 16; ++i) z16[i] = 0.f;

  for (int h = 0; h < 4; ++h) {
    // S^T[e][d] = sum_l k[e][l] q[d][l]  (K = LH = 16, one MFMA per 32x32 tile)
    const s8v qf = *reinterpret_cast<const s8v*>(&lds[QB + (2 * h + hi) * 2048 + (wid * 32 + lo) * 8]);
    f16v st[8];
#pragma unroll
    for (int et = 0; et < 8; ++et) {
      const s8v kf = *reinterpret_cast<const s8v*>(&lds[KB + (2 * h + hi) * 2048 + (et * 32 + lo) * 8]);
      st[et] = __builtin_amdgcn_mfma_f32_32x32x16_bf16(kf, qf, z16, 0, 0, 0);
    }
    // lane-local softmax over e (this lane + partner lane^32 hold all 256 e for col d)
    float m = -3.0e38f;
#pragma unroll
    for (int et = 0; et < 8; ++et)
#pragma unroll
      for (int r = 0; r < 16; ++r) m = fmaxf(m, st[et][r]);
    m = fmaxf(m, __shfl_xor(m, 32));
    const float m4 = 0.25f * m;
    float sum = 0.f;
#pragma unroll
    for (int et = 0; et < 8; ++et)
#pragma unroll
      for (int r = 0; r < 16; ++r) {
        const float p = __expf(0.25f * st[et][r] - m4);
        st[et][r] = p;
        sum += p;
      }
    sum += __shfl_xor(sum, 32);
    const float rinv = 1.0f / sum;

    // O^T[lh][d] = sum_e v^T[lh][e] P^T[e][d]
    f16v ot;
#pragma unroll
    for (int i = 0; i < 16; ++i) ot[i] = 0.f;
#pragma unroll
    for (int s = 0; s < 16; ++s) {
      const int et = s >> 1, s8o = (s & 1) * 8;
      const s8v vf = *reinterpret_cast<const s8v*>(
          &lds[VB + (2 * s + hi) * 512 + (h * 16 + (lane & 15)) * 8]);
      // build P^T B-frag: k = 8*hi + j, e = 16*s + k
      const u32 x0 = pk2(st[et][s8o + 0], st[et][s8o + 1]);
      const u32 x1 = pk2(st[et][s8o + 2], st[et][s8o + 3]);
      const u32 y0 = pk2(st[et][s8o + 4], st[et][s8o + 5]);
      const u32 y1 = pk2(st[et][s8o + 6], st[et][s8o + 7]);
      const u32 sx0 = (u32)__shfl_xor((int)x0, 32);
      const u32 sx1 = (u32)__shfl_xor((int)x1, 32);
      const u32 sy0 = (u32)__shfl_xor((int)y0, 32);
      const u32 sy1 = (u32)__shfl_xor((int)y1, 32);
      union { u32 u[4]; s8v v; } bu;
      bu.u[0] = hi ? sy0 : x0;
      bu.u[1] = hi ? sy1 : x1;
      bu.u[2] = hi ? y0 : sx0;
      bu.u[3] = hi ? y1 : sx1;
      ot = __builtin_amdgcn_mfma_f32_32x32x16_bf16(vf, bu.v, ot, 0, 0, 0);
    }
    // store normalized O^T into att buffer (XB region): ab[d>>3][l][d&7]
#pragma unroll
    for (int r = 0; r < 8; ++r) {
      const int lh = (r & 3) + 8 * (r >> 2) + 4 * hi;  // 0..15
      const int l = h * 16 + lh;
      const int d = wid * 32 + lo;
      lds[XB + (d >> 3) * 512 + l * 8 + (d & 7)] = f2bf(ot[r] * rinv);
    }
  }
  __syncthreads();

  proj_O(lds, wb + 196608, bo, out, base, wid, lo, hi);
}

extern "C" void kernel_launch(void* const* d_in, const int* in_sizes, int n_in,
                              void* d_out, int out_size, void* d_ws, size_t ws_size,
                              hipStream_t stream) {
  const float* xq = (const float*)d_in[0];
  const float* xk = (const float*)d_in[1];
  const float* xv = (const float*)d_in[2];
  const float* wq = (const float*)d_in[3];
  const float* bq = (const float*)d_in[4];
  const float* wk = (const float*)d_in[5];
  const float* bk = (const float*)d_in[6];
  const float* wv = (const float*)d_in[7];
  const float* bv = (const float*)d_in[8];
  const float* wo = (const float*)d_in[9];
  const float* bo = (const float*)d_in[10];
  u16* wsb = (u16*)d_ws;  // 4 * 65536 bf16 = 512 KB
  float* out = (float*)d_out;

  cvt_weights<<<dim3(256), dim3(256), 0, stream>>>(wq, wk, wv, wo, wsb);
  mha_kernel<<<dim3(1024), dim3(512), 0, stream>>>(xq, xk, xv, wsb, bq, bk, bv, bo, out);
}